// Round 3
// baseline (282.575 us; speedup 1.0000x reference)
//
#include <hip/hip_runtime.h>
#include <cstdint>
#include <cstddef>

// ---------------------------------------------------------------------------
// SpatialGRU 32x32, B=64, U=64, C=64. Persistent: 32 rows x 4 batch-tiles.
// R9: GEMM2 re-split by n (waves 4..7 own 16 out-cols each, full K=256) ->
// each wave holds complete h_hat preact in regs and FUSES tanh + softmax +
// combine + handoff store in one phase [E']. Eliminates pacc (LDS round
// trip), barrier s3, and the whole [F] phase: 3 barriers/iter (was 4).
//  - waves 0..3 run the hD<-hT rotation concurrently in [E'] span.
//  - qs32 hL/hD and qf's x slot are parity double-buffered (j&1) to remove
//    same-span read/write races created by the fusion.
//  - handoff: 4 halfword atomic stores per E' lane; consumer poll unchanged
//    (own dword per thread, both halves LSB=1; ws poison 0xAA fails).
//  - keeps R8's poll-overlapped GEMM1 split and XCD-affinity swizzle.
// ---------------------------------------------------------------------------

#define LDIM   32
#define BATCH  64
#define UNITS  64
#define CHAN   64
#define NBT    4
#define BT     16
#define TPB    512

typedef _Float16 f16;
typedef _Float16 f16x8 __attribute__((ext_vector_type(8)));
typedef float    f32x4 __attribute__((ext_vector_type(4)));

__global__ __launch_bounds__(TPB, 2) void spatial_gru_kernel(
    const float* __restrict__ x,     // (B, C, 32, 32)
    const float* __restrict__ W,     // (256, 448)
    const float* __restrict__ Urec,  // (192, 64)
    const float* __restrict__ bias,  // (512,)
    const float* __restrict__ Wij,   // (64, 64)
    float* __restrict__ out,         // (B, U)
    uint32_t* __restrict__ hbuf)     // (32, 32, NBT, 512 dw) f16[16][64]|LSB
{
    // XCD-affinity swizzle: physical block p -> XCD p%8; 4 consecutive rows
    // per XCD so most vertical handoffs stay on-die. Bijective on [0,128).
    const int p    = blockIdx.x;
    const int xcd  = p & 7;
    const int slot = p >> 3;         // 0..15
    const int row  = xcd * 4 + (slot >> 2);
    const int bt   = slot & 3;
    const int b0   = bt * BT;
    const int t    = (int)threadIdx.x;
    const int u    = t & 63;
    const int g    = t >> 6;         // wave id 0..7
    const int l15  = t & 15;         // MFMA n-col / A-row lane
    const int lq   = (t & 63) >> 4;  // MFMA k-quad

    // ---- LDS ----
    // qf  : GEMM1 A (f16) [b][k]: 0:64 hT | 64:128 hL | 128:192 hD |
    //       192:256 s(par0) | 256:320 s(par1)
    // rf  : GEMM2 A (f16) [b][0:192] = r*{hL,hT,hD}
    // qs32: fp32 state [b][c]: 0:64 hT | 64:128 hL0 | 128:192 hD0 |
    //       192:256 hL1 | 256:320 hD1   (hL/hD parity by j&1)
    // Gsz : z logits fp32 [b][0:256]
    __shared__ __attribute__((aligned(16))) f16 qf[BT][328];
    __shared__ __attribute__((aligned(16))) f16 rf[BT][200];
    __shared__ float qs32[BT][324];
    __shared__ float Gsz [BT][260];

    // ---- GEMM1 weights resident (waves 0..6: 64 cols each) ----
    f16x8 wreg[4][8];
    float bias1[4] = {0.f, 0.f, 0.f, 0.f};
    if (g < 7) {
        const int nb = g * 64 + l15;
#pragma unroll
        for (int T = 0; T < 4; ++T) {
            bias1[T] = bias[nb + 16 * T];
#pragma unroll
            for (int s = 0; s < 8; ++s) {
                f16x8 v;
#pragma unroll
                for (int jj = 0; jj < 8; ++jj) {
                    int kk = s * 32 + lq * 8 + jj;
                    v[jj] = (f16)W[(size_t)kk * 448 + nb + 16 * T];
                }
                wreg[T][s] = v;
            }
        }
    }
    // ---- GEMM2 weights: waves 4..7 hold FULL K=256 for 16 n-cols each ----
    f16x8 wreg2[8];
    float bijE = 0.f;
    if (g >= 4) {
        const int nn = (g - 4) * 16 + l15;
        bijE = bias[448 + nn];
#pragma unroll
        for (int s = 0; s < 8; ++s) {
            f16x8 v;
#pragma unroll
            for (int jj = 0; jj < 8; ++jj) {
                int kk = s * 32 + lq * 8 + jj;
                float wv = (kk < 192) ? Urec[kk * 64 + nn] : Wij[(kk - 192) * 64 + nn];
                v[jj] = (f16)wv;
            }
            wreg2[s] = v;
        }
    }

    // ---- zero init: all qs32 state, qf hT/hL/hD (0:192) ----
    for (int idx = t; idx < BT * 324; idx += TPB)
        ((float*)qs32)[idx] = 0.f;
    for (int idx = t; idx < 192 * BT; idx += TPB) {
        int b = idx & 15, k = idx >> 4;
        qf[b][k] = (f16)0.f;
    }

    // x: this thread handles channel u, batches b0+g and b0+g+8
    const size_t xb0 = (size_t)(b0 + g) * 65536 + (size_t)u * 1024 + (size_t)row * 32;
    const size_t xb1 = xb0 + (size_t)8 * 65536;
    {   // stage x(j=0) into parity-0 s slot
        float x0 = x[xb0], x1 = x[xb1];
        qf[g][192 + u]     = (f16)x0;
        qf[g + 8][192 + u] = (f16)x1;
    }

    for (int j = 0; j < LDIM; ++j) {
        const int par  = j & 1;
        const int scur = 192 + par * 64;
        const int snxt = 192 + (par ^ 1) * 64;
        const int hlc  = 64 + par * 128, hdc = 128 + par * 128;
        const int hln  = 64 + (par ^ 1) * 128, hdn = 128 + (par ^ 1) * 128;

        __syncthreads();   // s1 — prev-tail writes (h, rotations, x) visible

        // ---- [A] issue own-dword poll load (flies during [C-pre]) ----
        uint32_t wv_ = 0;
        const uint32_t* sp = hbuf;
        if (row > 0) {
            sp = hbuf + ((((size_t)(row - 1) * LDIM + j) * NBT + bt) << 9) + (g << 6) + u;
            wv_ = __hip_atomic_load(sp, __ATOMIC_RELAXED, __HIP_MEMORY_SCOPE_AGENT);
        }
        float nx0 = 0.f, nx1 = 0.f;
        if (j < LDIM - 1) { nx0 = x[xb0 + j + 1]; nx1 = x[xb1 + j + 1]; }

        // ---- [C-pre] GEMM1 k=64:256 (waves 0..6; hL/hD/s all local) ----
        f32x4 acc[4];
        if (g < 7) {
#pragma unroll
            for (int T = 0; T < 4; ++T)
                acc[T] = (f32x4){bias1[T], bias1[T], bias1[T], bias1[T]};
#pragma unroll
            for (int s = 2; s < 8; ++s) {
                const f16* ap = (s < 6) ? &qf[l15][s * 32 + lq * 8]
                                        : &qf[l15][scur + (s - 6) * 32 + lq * 8];
                f16x8 a = *(const f16x8*)ap;
#pragma unroll
                for (int T = 0; T < 4; ++T)
                    acc[T] = __builtin_amdgcn_mfma_f32_16x16x32_f16(a, wreg[T][s], acc[T], 0, 0, 0);
            }
        }

        // ---- [A'] complete poll; unpack + stage hT (thread-own slots) ----
        {
            float ht0 = 0.f, ht1 = 0.f;
            f16 hf0 = (f16)0.f, hf1 = (f16)0.f;
            if (row > 0) {
                while ((wv_ & 0x00010001u) != 0x00010001u) {
                    __builtin_amdgcn_s_sleep(1);
                    wv_ = __hip_atomic_load(sp, __ATOMIC_RELAXED, __HIP_MEMORY_SCOPE_AGENT);
                }
                uint16_t lo = (uint16_t)(wv_ & 0xFFFFu), hi = (uint16_t)(wv_ >> 16);
                hf0 = __builtin_bit_cast(f16, lo);
                hf1 = __builtin_bit_cast(f16, hi);
                ht0 = (float)hf0;
                ht1 = (float)hf1;
            }
            qs32[g][u]     = ht0;  qf[g][u]     = hf0;
            qs32[g + 8][u] = ht1;  qf[g + 8][u] = hf1;
        }
        __syncthreads();   // s1b — hT staged visible

        // ---- [C-post] GEMM1 k=0:64 (waves 0..6) + sigmoid/z dumps ----
        if (g < 7) {
            {
                f16x8 a0 = *(const f16x8*)&qf[l15][lq * 8];
                f16x8 a1 = *(const f16x8*)&qf[l15][32 + lq * 8];
#pragma unroll
                for (int T = 0; T < 4; ++T)
                    acc[T] = __builtin_amdgcn_mfma_f32_16x16x32_f16(a0, wreg[T][0], acc[T], 0, 0, 0);
#pragma unroll
                for (int T = 0; T < 4; ++T)
                    acc[T] = __builtin_amdgcn_mfma_f32_16x16x32_f16(a1, wreg[T][1], acc[T], 0, 0, 0);
            }
            if (g < 3) {
                // g=0: r*hL -> rf 0:64 ; g=1: r*hT -> rf 64:128 ; g=2: r*hD -> rf 128:192
                const int colbase = (g == 0) ? hlc : (g == 1) ? 0 : hdc;
#pragma unroll
                for (int T = 0; T < 4; ++T)
#pragma unroll
                    for (int r = 0; r < 4; ++r) {
                        float rr = 1.f / (1.f + __expf(-acc[T][r]));
                        int b = lq * 4 + r;
                        float hv = qs32[b][colbase + T * 16 + l15];
                        rf[b][g * 64 + T * 16 + l15] = (f16)(rr * hv);
                    }
            } else {
                const int zb = (g - 3) * 64;
#pragma unroll
                for (int T = 0; T < 4; ++T)
#pragma unroll
                    for (int r = 0; r < 4; ++r)
                        Gsz[lq * 4 + r][zb + T * 16 + l15] = acc[T][r];
            }
        }
        __syncthreads();   // s2 — rf + Gsz ready

        // ---- [E'] waves 4..7: full-K GEMM2 (8 MFMA, 2 accs) + fused
        //      tanh/softmax/combine + handoff stores + hL rotation.
        //      waves 0..3: hD<-hT parity rotation. ----
        if (g >= 4) {
            f32x4 aA = (f32x4){0.f, 0.f, 0.f, 0.f};
            f32x4 aB = (f32x4){0.f, 0.f, 0.f, 0.f};
#pragma unroll
            for (int s = 0; s < 8; s += 2) {
                const f16* apA = (s < 6) ? &rf[l15][s * 32 + lq * 8]
                                         : &qf[l15][scur + (s - 6) * 32 + lq * 8];
                f16x8 a = *(const f16x8*)apA;
                aA = __builtin_amdgcn_mfma_f32_16x16x32_f16(a, wreg2[s], aA, 0, 0, 0);
                const f16* apB = (s + 1 < 6) ? &rf[l15][(s + 1) * 32 + lq * 8]
                                             : &qf[l15][scur + (s + 1 - 6) * 32 + lq * 8];
                f16x8 b_ = *(const f16x8*)apB;
                aB = __builtin_amdgcn_mfma_f32_16x16x32_f16(b_, wreg2[s + 1], aB, 0, 0, 0);
            }
            const int n = (g - 4) * 16 + l15;
            uint16_t* hp = (uint16_t*)(hbuf + ((((size_t)row * LDIM + j) * NBT + bt) << 9));
#pragma unroll
            for (int rr = 0; rr < 4; ++rr) {
                const int b = lq * 4 + rr;
                float hh = bijE + aA[rr] + aB[rr];
                float e2 = __expf(2.f * hh);
                float th = 1.f - 2.f / (e2 + 1.f);          // tanh
                float zi = Gsz[b][n],       zl = Gsz[b][64 + n];
                float zt = Gsz[b][128 + n], zd = Gsz[b][192 + n];
                float hT = qs32[b][n], hL = qs32[b][hlc + n], hD = qs32[b][hdc + n];
                float mx = fmaxf(fmaxf(zi, zl), fmaxf(zt, zd));
                float ei = __expf(zi - mx), el = __expf(zl - mx);
                float et = __expf(zt - mx), ed = __expf(zd - mx);
                float inv = 1.f / (ei + el + et + ed);
                float h = (el * hL + et * hT + ed * hD + ei * th) * inv;
                // handoff: halfword store; dword (b&7)<<6|n gets lo=b, hi=b+8
                uint16_t hv16 = (uint16_t)(__builtin_bit_cast(uint16_t, (f16)h) | 1u);
                __hip_atomic_store(hp + ((((b & 7) << 6) + n) << 1) + (b >> 3),
                                   hv16, __ATOMIC_RELAXED, __HIP_MEMORY_SCOPE_AGENT);
                // rotation: hL(next parity) <- h
                qs32[b][hln + n] = h;
                qf[b][64 + n]    = (f16)h;
                if (row == LDIM - 1 && j == LDIM - 1)
                    out[(size_t)(b0 + b) * UNITS + n] = h;
            }
        } else {
            // waves 0..3: hD(next parity) <- hT (this iter), qs32 + qf
#pragma unroll
            for (int i = 0; i < 4; ++i) {
                const int b = g + 4 * i;
                qs32[b][hdn + u] = qs32[b][u];
                qf[b][128 + u]   = qf[b][u];
            }
        }
        // stage next x into parity-next s slot (thread-own; read next iter)
        qf[g][snxt + u]     = (f16)nx0;
        qf[g + 8][snxt + u] = (f16)nx1;
        // next s1 covers cross-wave visibility of all tail writes
    }
}

extern "C" void kernel_launch(void* const* d_in, const int* in_sizes, int n_in,
                              void* d_out, int out_size, void* d_ws, size_t ws_size,
                              hipStream_t stream) {
    const float* x    = (const float*)d_in[0];
    const float* W    = (const float*)d_in[1];
    const float* Urec = (const float*)d_in[2];
    const float* bias = (const float*)d_in[3];
    const float* Wij  = (const float*)d_in[4];
    float* out = (float*)d_out;

    // hbuf: 32*32*4*512 dwords = 8 MB. Harness re-poisons ws with 0xAA each
    // launch; 0xAAAA halfwords fail the per-half LSB validity test.
    uint32_t* hbuf = (uint32_t*)d_ws;

    spatial_gru_kernel<<<LDIM * NBT, TPB, 0, stream>>>(
        x, W, Urec, bias, Wij, out, hbuf);
}